// Round 12
// baseline (142.237 us; speedup 1.0000x reference)
//
#include <hip/hip_runtime.h>

#define NSER 65536
#define NT   1024
#define SEAS 24
#define SLEN (NT + SEAS)   // 1048 seasonal output columns
#define NSB  10            // main superblocks of 4 windows (96 steps): t = 0..959
#define LST  104           // LDS row stride (96 data + 8 pad)

typedef float v4f __attribute__((ext_vector_type(4)));  // native vector type:
// required by __builtin_nontemporal_* (HIP_vector_type float4 is rejected)

__device__ __forceinline__ float frcp(float x) { return __builtin_amdgcn_rcpf(x); }

// DPP move; bound_ctrl=1 -> out-of-range sources read 0.0f; rows masked out of
// RMASK receive the OLD operand (0.0f).  0x110+N = row_shr:N (16-lane rows);
// 0x142 = row_bcast15 (15->16..31, 31->32..47, 47->48..63 — RMASK=0xA keeps
// rows 1,3 only, severing the lane31 -> group-B path structurally).
template<int CTRL, int RMASK = 0xF>
__device__ __forceinline__ float dpp0(float x) {
    return __int_as_float(
        __builtin_amdgcn_update_dpp(0, __float_as_int(x), CTRL, RMASK, 0xF, true));
}

// One 32-lane group per series, lane j owns t = 24*w + j (j < 24).
// Weighted inclusive scan per window on the VALU via DPP; carry via readlane.
// 4-window superblocks staged through wave-private LDS: all main VMEM is
// full-line v4f (nt load for y, nt store for levels; seasout normal so its
// misaligned edge lines merge in L2). Tail (t=960..1023) staged the same way.
// y prefetch is 2 superblocks deep (~800+ cy of wave work ahead of use).
__global__ __launch_bounds__(256, 8) void es_dpp6_kernel(
    const float* __restrict__ y,
    const int*   __restrict__ idxs,
    const float* __restrict__ lev_sms,
    const float* __restrict__ seas_sms,
    const float* __restrict__ init_seas,
    float* __restrict__ levels,
    float* __restrict__ seasout)
{
    __shared__ float ybuf [8][LST];
    __shared__ float lvbuf[8][LST];
    __shared__ float nsbuf[8][LST];

    const int tid = threadIdx.x;
    const int grp = tid >> 5;                 // 8 series per 256-thread block
    const int j   = tid & 31;                 // lane within group; j<24 active
    const int i   = blockIdx.x * 8 + grp;     // series index
    const bool act = (j < SEAS);

    // pad init: indices 96..103 (read by lanes j>=24 in main window k=3)
    if (!act) ybuf[grp][72 + j] = 1.0f;

    const int id = idxs[i];
    const float a  = 1.0f / (1.0f + __expf(-lev_sms[id]));
    const float b  = 1.0f / (1.0f + __expf(-seas_sms[id]));
    const float ia = 1.0f - a, ib = 1.0f - b;

    const float ia1 = ia, ia2 = ia1*ia1, ia4 = ia2*ia2, ia8 = ia4*ia4;
    const float iapow = __powf(ia, (float)(j + 1));
    const float wbc   = (j >= 16 && j < SEAS) ? __powf(ia, (float)(j - 15)) : 0.0f;

    const size_t lrow = (size_t)i * NT;
    const size_t srow = (size_t)i * SLEN;
    const float* yrow = y + lrow;

    // initial seasonal state s = exp(init_seas[id][j]); emit cols 0..23
    float s = 1.0f;
    if (act) {
        s = __expf(init_seas[(size_t)id * SEAS + j]);
        seasout[srow + j] = s;
    }

    float lev_prev = 0.0f;

    // per-window scan core (DPP, all-VALU; carry via readlane)
    auto window = [&](float ycur, float ae, float be, float ibe) -> float2 {
        float x = ae * ycur * frcp(s);
        x = fmaf(ia1, dpp0<0x111>(x), x);          // row_shr:1
        x = fmaf(ia2, dpp0<0x112>(x), x);          // row_shr:2
        x = fmaf(ia4, dpp0<0x114>(x), x);          // row_shr:4
        x = fmaf(ia8, dpp0<0x118>(x), x);          // row_shr:8
        x = fmaf(wbc, dpp0<0x142, 0xA>(x), x);     // row_bcast15, rows 1&3 only
        const float lev = fmaf(iapow, lev_prev, x);
        const float ns  = fmaf(ibe, s, be * ycur * frcp(lev));
        const int li = __float_as_int(lev);
        const float cA = __int_as_float(__builtin_amdgcn_readlane(li, 23));
        const float cB = __int_as_float(__builtin_amdgcn_readlane(li, 55));
        lev_prev = (tid & 32) ? cB : cA;
        s = ns;
        return make_float2(lev, ns);
    };

    // 2-deep prefetch: superblocks 0 and 1 in flight before any compute
    v4f yp0 = (v4f){1.f, 1.f, 1.f, 1.f};
    v4f yp1 = (v4f){1.f, 1.f, 1.f, 1.f};
    if (act) {
        yp0 = __builtin_nontemporal_load((const v4f*)(yrow + 4 * j));
        yp1 = __builtin_nontemporal_load((const v4f*)(yrow + 96 + 4 * j));
    }

    for (int u = 0; u < NSB; ++u) {
        // stage current superblock's y (wave-private LDS; lgkmcnt only)
        if (act) *(v4f*)&ybuf[grp][4 * j] = yp0;
        yp0 = yp1;

        // issue load for superblock u+2 (or the 64-float tail at u+2 == NSB)
        if (u + 2 < NSB) {
            if (act)
                yp1 = __builtin_nontemporal_load(
                    (const v4f*)(yrow + 96 * (u + 2) + 4 * j));
        } else if (u + 2 == NSB) {
            if (j < 16)
                yp1 = __builtin_nontemporal_load((const v4f*)(yrow + 960 + 4 * j));
        }

        const bool first = (u == 0);
        #pragma unroll
        for (int k = 0; k < 4; ++k) {
            const float ycur = ybuf[grp][24 * k + j];   // ds_read transpose
            float ae = a, be = b, ibe = ib;
            if (first && k == 0 && j == 0) { ae = 1.0f; be = 0.0f; ibe = 1.0f; }
            const float2 r = window(ycur, ae, be, ibe);
            lvbuf[grp][24 * k + j] = r.x;
            nsbuf[grp][24 * k + j] = r.y;
        }

        // flush: full-line v4f (384 B contiguous per series per array)
        if (act) {
            const v4f lvv = *(v4f*)&lvbuf[grp][4 * j];
            const v4f nsv = *(v4f*)&nsbuf[grp][4 * j];
            __builtin_nontemporal_store(lvv, (v4f*)(levels + lrow + 96 * u + 4 * j));
            *(v4f*)(seasout + srow + SEAS + 96 * u + 4 * j) = nsv;
        }
    }

    // ---- staged tail: t = 960..1023 (windows 40,41 full + 42 = 16 steps) ----
    if (j < 16) *(v4f*)&ybuf[grp][4 * j] = yp0;      // stage 64 floats (0..63)
    else        ybuf[grp][48 + j] = 1.0f;            // pad 64..79 finite

    #pragma unroll
    for (int k = 0; k < 3; ++k) {
        const float ycur = ybuf[grp][24 * k + j];
        const float2 r = window(ycur, a, b, ib);
        lvbuf[grp][24 * k + j] = r.x;   // k=2, j>=16 lands at 64..79 (unused)
        nsbuf[grp][24 * k + j] = r.y;
    }

    if (j < 16) {
        const v4f lvv = *(v4f*)&lvbuf[grp][4 * j];
        const v4f nsv = *(v4f*)&nsbuf[grp][4 * j];
        __builtin_nontemporal_store(lvv, (v4f*)(levels + lrow + 960 + 4 * j));
        *(v4f*)(seasout + srow + SEAS + 960 + 4 * j) = nsv;
    }
}

extern "C" void kernel_launch(void* const* d_in, const int* in_sizes, int n_in,
                              void* d_out, int out_size, void* d_ws, size_t ws_size,
                              hipStream_t stream) {
    const float* y         = (const float*)d_in[0];
    const int*   idxs      = (const int*)d_in[1];
    const float* lev_sms   = (const float*)d_in[2];
    const float* seas_sms  = (const float*)d_in[3];
    const float* init_seas = (const float*)d_in[4];

    float* levels  = (float*)d_out;
    float* seasout = levels + (size_t)NSER * NT;

    es_dpp6_kernel<<<NSER/8, 256, 0, stream>>>(y, idxs, lev_sms, seas_sms, init_seas,
                                               levels, seasout);
}